// Round 5
// baseline (269.116 us; speedup 1.0000x reference)
//
#include <hip/hip_runtime.h>

#define B_ 32
#define H_ 4
#define S_ 4096
#define M_ 128
#define ST 128                 // rows per block
#define NB (S_ / ST)           // 32 blocks per batch; grid = 32 x 32 = 1024
#define EPS_ 1e-8f
#define MAGIC 0x5F3759DFu

// Single-dispatch fused DNC memory op with PER-BATCH producer/consumer sync
// (not a grid barrier: blocks only wait for their own batch's 32 siblings,
// so full occupancy is preserved and no co-residency of the whole grid is
// required for progress). Phase 1: u = exp(beta*cossim) into LDS + Zp
// partials to global (agent-scope) + flag release. Wait on 32 flags.
// Phase 2: normalize in LDS, erase/add in-flight, read-accumulate, atomicAdd.
__global__ __launch_bounds__(256, 4) void k_fused(
    const float* __restrict__ mem, const float* __restrict__ kk,
    const float* __restrict__ beta, const float* __restrict__ er,
    const float* __restrict__ ad, float* __restrict__ out,
    float* __restrict__ Zp, unsigned int* __restrict__ flags)
{
  const int b   = blockIdx.y;
  const int blk = blockIdx.x;
  const int s0  = blk * ST;
  const int tid = threadIdx.x;
  const int wv   = tid >> 6;
  const int lane = tid & 63;
  const int g    = lane >> 4;   // row-in-quad (0..3)
  const int i    = lane & 15;   // column-group (8 cols each)

  __shared__ float su[H_ * ST];    // [h][row]: u, then normalized w
  __shared__ float red[4 * 512];   // phase-2 reduction scratch
  __shared__ float zinv[H_];

  // designated block zeroes out[b] (visible before its flag is released)
  if (blk == 0) {
    float* ob = out + b * H_ * M_;
    __hip_atomic_store(&ob[tid], 0.f, __ATOMIC_RELAXED, __HIP_MEMORY_SCOPE_AGENT);
    __hip_atomic_store(&ob[tid + 256], 0.f, __ATOMIC_RELAXED, __HIP_MEMORY_SCOPE_AGENT);
  }

  // ---------------- phase 1: unnormalized softmax numerators ----------------
  float4 kf0[H_], kf1[H_];
  const float* kbase = kk + b * H_ * M_ + i * 8;
#pragma unroll
  for (int h = 0; h < H_; ++h) {
    kf0[h] = *(const float4*)(kbase + h * M_);
    kf1[h] = *(const float4*)(kbase + h * M_ + 4);
  }

  float coef[H_];
#pragma unroll
  for (int h = 0; h < H_; ++h) {
    float sq = kf0[h].x*kf0[h].x + kf0[h].y*kf0[h].y + kf0[h].z*kf0[h].z + kf0[h].w*kf0[h].w
             + kf1[h].x*kf1[h].x + kf1[h].y*kf1[h].y + kf1[h].z*kf1[h].z + kf1[h].w*kf1[h].w;
#pragma unroll
    for (int msk = 1; msk < 16; msk <<= 1) sq += __shfl_xor(sq, msk, 64);
    coef[h] = beta[b * H_ + h] / fmaxf(sqrtf(sq), EPS_);
  }
  const float cw = (i == 0) ? coef[0] : (i == 1) ? coef[1] : (i == 2) ? coef[2] : coef[3];

  for (int it = 0; it < ST / 16; ++it) {
    const int rloc = it * 16 + wv * 4 + g;
    const float* row = mem + ((size_t)(b * S_ + s0 + rloc)) * M_ + i * 8;
    const float4 v0 = *(const float4*)(row);
    const float4 v1 = *(const float4*)(row + 4);

    float sq = v0.x*v0.x + v0.y*v0.y + v0.z*v0.z + v0.w*v0.w
             + v1.x*v1.x + v1.y*v1.y + v1.z*v1.z + v1.w*v1.w;
    float d[H_];
#pragma unroll
    for (int h = 0; h < H_; ++h) {
      d[h] = v0.x*kf0[h].x + v0.y*kf0[h].y + v0.z*kf0[h].z + v0.w*kf0[h].w
           + v1.x*kf1[h].x + v1.y*kf1[h].y + v1.z*kf1[h].z + v1.w*kf1[h].w;
    }
#pragma unroll
    for (int msk = 1; msk < 16; msk <<= 1) {
      sq += __shfl_xor(sq, msk, 64);
#pragma unroll
      for (int h = 0; h < H_; ++h) d[h] += __shfl_xor(d[h], msk, 64);
    }
    if (i < H_) {
      const float dv = (i == 0) ? d[0] : (i == 1) ? d[1] : (i == 2) ? d[2] : d[3];
      // no max-subtraction: |beta*cossim| < 1 by construction, exp safe
      su[i * ST + rloc] = __expf(dv * cw / fmaxf(sqrtf(sq), EPS_));
    }
  }
  __syncthreads();

  // per-head block partial Z -> Zp (agent-scope store, race-free slot)
  {
    const float* p = su + wv * ST;
    float vs = p[lane] + p[lane + 64];
#pragma unroll
    for (int msk = 1; msk < 64; msk <<= 1) vs += __shfl_xor(vs, msk, 64);
    if (lane == 0)
      __hip_atomic_store(&Zp[(b * NB + blk) * H_ + wv], vs,
                         __ATOMIC_RELAXED, __HIP_MEMORY_SCOPE_AGENT);
  }
  // __syncthreads drains vmcnt; then one thread publishes the flag
  __syncthreads();
  __threadfence();
  if (tid == 0)
    __hip_atomic_store(&flags[b * NB + blk], MAGIC,
                       __ATOMIC_RELEASE, __HIP_MEMORY_SCOPE_AGENT);

  // ---------------- per-batch sync: wait for this batch's 32 flags ----------
  if (lane < NB) {
    while (__hip_atomic_load(&flags[b * NB + lane],
                             __ATOMIC_ACQUIRE, __HIP_MEMORY_SCOPE_AGENT) != MAGIC)
      __builtin_amdgcn_s_sleep(2);
  }

  // each wave reduces its head's 32 partials (lanes 0..31)
  {
    float z = 0.f;
    if (lane < NB)
      z = __hip_atomic_load(&Zp[(b * NB + lane) * H_ + wv],
                            __ATOMIC_RELAXED, __HIP_MEMORY_SCOPE_AGENT);
#pragma unroll
    for (int msk = 1; msk < NB; msk <<= 1) z += __shfl_xor(z, msk, 64);
    if (lane == 0) zinv[wv] = 1.0f / z;
  }
  __syncthreads();

  for (int j = tid; j < H_ * ST; j += 256) su[j] *= zinv[j >> 7];
  __syncthreads();

  // ---------------- phase 2: erase/add in-flight + read ---------------------
  const int c  = tid & 31;   // cols [4c, 4c+4)
  const int rr = tid >> 5;   // row slot (0..7)

  float4 e4[H_], a4[H_];
  const int base = b * H_ * M_ + c * 4;
#pragma unroll
  for (int h = 0; h < H_; ++h) {
    e4[h] = *(const float4*)(er + base + h * M_);
    a4[h] = *(const float4*)(ad + base + h * M_);
  }

  float4 acc[H_];
#pragma unroll
  for (int h = 0; h < H_; ++h) acc[h] = make_float4(0.f, 0.f, 0.f, 0.f);

  for (int it = 0; it < ST / 8; ++it) {
    const int r = it * 8 + rr;
    float4 x = *(const float4*)(mem + ((size_t)(b * S_ + s0 + r)) * M_ + c * 4);
    const float w0 = su[0 * ST + r], w1 = su[1 * ST + r];
    const float w2 = su[2 * ST + r], w3 = su[3 * ST + r];

    x.x = x.x * (1.f - w0 * e4[0].x) + w0 * a4[0].x;
    x.y = x.y * (1.f - w0 * e4[0].y) + w0 * a4[0].y;
    x.z = x.z * (1.f - w0 * e4[0].z) + w0 * a4[0].z;
    x.w = x.w * (1.f - w0 * e4[0].w) + w0 * a4[0].w;
    x.x = x.x * (1.f - w1 * e4[1].x) + w1 * a4[1].x;
    x.y = x.y * (1.f - w1 * e4[1].y) + w1 * a4[1].y;
    x.z = x.z * (1.f - w1 * e4[1].z) + w1 * a4[1].z;
    x.w = x.w * (1.f - w1 * e4[1].w) + w1 * a4[1].w;
    x.x = x.x * (1.f - w2 * e4[2].x) + w2 * a4[2].x;
    x.y = x.y * (1.f - w2 * e4[2].y) + w2 * a4[2].y;
    x.z = x.z * (1.f - w2 * e4[2].z) + w2 * a4[2].z;
    x.w = x.w * (1.f - w2 * e4[2].w) + w2 * a4[2].w;
    x.x = x.x * (1.f - w3 * e4[3].x) + w3 * a4[3].x;
    x.y = x.y * (1.f - w3 * e4[3].y) + w3 * a4[3].y;
    x.z = x.z * (1.f - w3 * e4[3].z) + w3 * a4[3].z;
    x.w = x.w * (1.f - w3 * e4[3].w) + w3 * a4[3].w;

    acc[0].x += w0 * x.x; acc[0].y += w0 * x.y; acc[0].z += w0 * x.z; acc[0].w += w0 * x.w;
    acc[1].x += w1 * x.x; acc[1].y += w1 * x.y; acc[1].z += w1 * x.z; acc[1].w += w1 * x.w;
    acc[2].x += w2 * x.x; acc[2].y += w2 * x.y; acc[2].z += w2 * x.z; acc[2].w += w2 * x.w;
    acc[3].x += w3 * x.x; acc[3].y += w3 * x.y; acc[3].z += w3 * x.z; acc[3].w += w3 * x.w;
  }

  // reduce rr pairs within each wave (lanes 0..31 keep the pair sum)
#pragma unroll
  for (int h = 0; h < H_; ++h) {
    acc[h].x += __shfl_xor(acc[h].x, 32, 64);
    acc[h].y += __shfl_xor(acc[h].y, 32, 64);
    acc[h].z += __shfl_xor(acc[h].z, 32, 64);
    acc[h].w += __shfl_xor(acc[h].w, 32, 64);
  }
  if (lane < 32) {
#pragma unroll
    for (int h = 0; h < H_; ++h) {
      red[wv * 512 + (h * 4 + 0) * 32 + lane] = acc[h].x;
      red[wv * 512 + (h * 4 + 1) * 32 + lane] = acc[h].y;
      red[wv * 512 + (h * 4 + 2) * 32 + lane] = acc[h].z;
      red[wv * 512 + (h * 4 + 3) * 32 + lane] = acc[h].w;
    }
  }
  __syncthreads();

  for (int j = tid; j < 512; j += 256) {
    const float val = red[j] + red[512 + j] + red[1024 + j] + red[1536 + j];
    const int h = j >> 7, comp = (j >> 5) & 3, cc = j & 31;
    atomicAdd(&out[b * H_ * M_ + h * M_ + cc * 4 + comp], val);
  }
}

extern "C" void kernel_launch(void* const* d_in, const int* in_sizes, int n_in,
                              void* d_out, int out_size, void* d_ws, size_t ws_size,
                              hipStream_t stream) {
  const float* mem  = (const float*)d_in[0];
  const float* kk   = (const float*)d_in[1];
  const float* beta = (const float*)d_in[2];
  const float* er   = (const float*)d_in[3];
  const float* ad   = (const float*)d_in[4];
  float* out = (float*)d_out;

  unsigned int* flags = (unsigned int*)d_ws;                 // B*NB = 1024 words
  float* Zp = (float*)((char*)d_ws + 4096);                  // (B,NB,H) floats

  dim3 grid(NB, B_);   // 32 x 32 = 1024 blocks, 4 blocks/CU
  k_fused<<<grid, 256, 0, stream>>>(mem, kk, beta, er, ad, out, Zp, flags);
}

// Round 6
// 113.389 us; speedup vs baseline: 2.3734x; 2.3734x over previous
//
#include <hip/hip_runtime.h>

#define B_ 32
#define H_ 4
#define S_ 4096
#define M_ 128
#define EPS_ 1e-8f

#define ST1 128            // rows per k1 block
#define NB1 (S_ / ST1)     // 32 k1 blocks per batch
#define ST3 128            // rows per k2 block — SAME grid shape as k1 so the
                           // linearized block id (and thus XCD assignment)
                           // matches k1's: k2 re-reads rows its XCD's L2 holds.

// ---------------------------------------------------------------------------
// Kernel 1: u[b,h,s] = exp(beta/||k|| * dot(k, mem_s)/||mem_s||)  (no max-sub:
// arg in (-1,1) since beta in [0,1), |cossim|<=1). Writes race-free per-block
// partial sums Zp[b,h,blk] (no memset, no atomics). blockIdx.x==0 blocks also
// zero out[] — safe, k2 is a later dispatch. Layout: 8 lanes/row x 8 rows/wave.
// ---------------------------------------------------------------------------
__global__ __launch_bounds__(256) void k_scores(
    const float* __restrict__ mem, const float* __restrict__ kk,
    const float* __restrict__ beta, float* __restrict__ sc,
    float* __restrict__ Zp, float* __restrict__ out)
{
  const int b   = blockIdx.y;
  const int s0  = blockIdx.x * ST1;
  const int tid = threadIdx.x;
  const int wv   = tid >> 6;
  const int lane = tid & 63;
  const int g    = lane >> 3;   // row-in-wave (0..7)
  const int i    = lane & 7;    // column-group (16 cols each)

  // zero the output accumulator (replaces a memset dispatch)
  if (blockIdx.x == 0)
    ((float2*)(out + b * H_ * M_))[tid] = make_float2(0.f, 0.f);

  // per-lane k fragments: cols [i*16, i*16+16) for each head
  float4 kf[H_][4];
  const float* kbase = kk + b * H_ * M_ + i * 16;
#pragma unroll
  for (int h = 0; h < H_; ++h)
#pragma unroll
    for (int q = 0; q < 4; ++q)
      kf[h][q] = *(const float4*)(kbase + h * M_ + q * 4);

  float coef[H_];
#pragma unroll
  for (int h = 0; h < H_; ++h) {
    float sq = 0.f;
#pragma unroll
    for (int q = 0; q < 4; ++q)
      sq += kf[h][q].x*kf[h][q].x + kf[h][q].y*kf[h][q].y
          + kf[h][q].z*kf[h][q].z + kf[h][q].w*kf[h][q].w;
#pragma unroll
    for (int msk = 1; msk < 8; msk <<= 1) sq += __shfl_xor(sq, msk, 64);
    coef[h] = beta[b * H_ + h] / fmaxf(sqrtf(sq), EPS_);
  }
  const float cw = (i == 0) ? coef[0] : (i == 1) ? coef[1] : (i == 2) ? coef[2] : coef[3];

  __shared__ float su[ST1 * 5];  // [row][head], stride-5 (conflict-free)

  for (int it = 0; it < ST1 / 32; ++it) {
    const int rloc = it * 32 + wv * 8 + g;
    const int s = s0 + rloc;
    const float* row = mem + ((size_t)(b * S_ + s)) * M_ + i * 16;
    float4 v[4];
#pragma unroll
    for (int q = 0; q < 4; ++q) v[q] = *(const float4*)(row + q * 4);

    float sq = 0.f;
    float d[H_] = {0.f, 0.f, 0.f, 0.f};
#pragma unroll
    for (int q = 0; q < 4; ++q) {
      sq += v[q].x*v[q].x + v[q].y*v[q].y + v[q].z*v[q].z + v[q].w*v[q].w;
#pragma unroll
      for (int h = 0; h < H_; ++h)
        d[h] += v[q].x*kf[h][q].x + v[q].y*kf[h][q].y
              + v[q].z*kf[h][q].z + v[q].w*kf[h][q].w;
    }
#pragma unroll
    for (int msk = 1; msk < 8; msk <<= 1) {
      sq += __shfl_xor(sq, msk, 64);
#pragma unroll
      for (int h = 0; h < H_; ++h) d[h] += __shfl_xor(d[h], msk, 64);
    }
    if (i < H_) {
      const float dv = (i == 0) ? d[0] : (i == 1) ? d[1] : (i == 2) ? d[2] : d[3];
      const float mn = fmaxf(sqrtf(sq), EPS_);
      su[rloc * 5 + i] = __expf(dv * cw / mn);
    }
  }
  __syncthreads();

  // per-head block partial Z -> Zp (race-free slot per block)
  {
    float vs = su[lane * 5 + wv] + su[(lane + 64) * 5 + wv];
#pragma unroll
    for (int msk = 1; msk < 64; msk <<= 1) vs += __shfl_xor(vs, msk, 64);
    if (lane == 0) Zp[(b * H_ + wv) * NB1 + blockIdx.x] = vs;
  }

  // coalesced store: wave h stores 128 contiguous floats of head h
  const int h = tid >> 6, j = tid & 63;
  float* dst = sc + ((size_t)(b * H_ + h)) * S_ + s0;
  dst[j]      = su[j * 5 + h];
  dst[j + 64] = su[(j + 64) * 5 + h];
}

// ---------------------------------------------------------------------------
// Kernel 2: second (L2/L3-hot) pass over memory, grid shape identical to k1
// for XCD affinity. Z reduced from Zp partials in registers; w = u/Z staged
// in LDS via float4; nmem computed in-flight; float4 loads; block-level LDS
// reduction then few atomics into out.
// ---------------------------------------------------------------------------
__global__ __launch_bounds__(256) void k_writeread(
    const float* __restrict__ mem, const float* __restrict__ sc,
    const float* __restrict__ Zp, const float* __restrict__ er,
    const float* __restrict__ ad, float* __restrict__ out)
{
  const int b   = blockIdx.y;
  const int s0  = blockIdx.x * ST3;
  const int tid = threadIdx.x;
  const int wv = tid >> 6, lane = tid & 63;

  __shared__ float sw[H_ * ST3];   // normalized weights for this S-block
  __shared__ float red[4 * 512];   // per-wave partial reading
  __shared__ float zinv[H_];

  // wave wv reduces head wv's 32 partials (lanes 0..31 exchange among selves)
  {
    float z = (lane < NB1) ? Zp[(b * H_ + wv) * NB1 + lane] : 0.f;
#pragma unroll
    for (int msk = 1; msk < NB1; msk <<= 1) z += __shfl_xor(z, msk, 64);
    if (lane == 0) zinv[wv] = 1.0f / z;
  }
  __syncthreads();

  // stage normalized weights: 512 floats = 128 float4, threads 0..127
  if (tid < H_ * ST3 / 4) {
    const int h = tid >> 5;  // 32 float4 per head (128 floats)
    float4 u4 = *(const float4*)(sc + ((size_t)(b * H_ + h)) * S_ + s0 + (tid & 31) * 4);
    const float zi = zinv[h];
    u4.x *= zi; u4.y *= zi; u4.z *= zi; u4.w *= zi;
    *(float4*)(sw + tid * 4) = u4;
  }
  __syncthreads();

  const int c  = tid & 31;   // column group: cols [4c, 4c+4)
  const int rr = tid >> 5;   // row slot (0..7)

  float4 e4[H_], a4[H_];
  const int base = b * H_ * M_ + c * 4;
#pragma unroll
  for (int h = 0; h < H_; ++h) {
    e4[h] = *(const float4*)(er + base + h * M_);
    a4[h] = *(const float4*)(ad + base + h * M_);
  }

  float4 acc[H_];
#pragma unroll
  for (int h = 0; h < H_; ++h) acc[h] = make_float4(0.f, 0.f, 0.f, 0.f);

  for (int it = 0; it < ST3 / 8; ++it) {
    const int r = it * 8 + rr;
    const int s = s0 + r;
    float4 x = *(const float4*)(mem + ((size_t)(b * S_ + s)) * M_ + c * 4);
    const float w0 = sw[0 * ST3 + r], w1 = sw[1 * ST3 + r];
    const float w2 = sw[2 * ST3 + r], w3 = sw[3 * ST3 + r];

    x.x = x.x * (1.f - w0 * e4[0].x) + w0 * a4[0].x;
    x.y = x.y * (1.f - w0 * e4[0].y) + w0 * a4[0].y;
    x.z = x.z * (1.f - w0 * e4[0].z) + w0 * a4[0].z;
    x.w = x.w * (1.f - w0 * e4[0].w) + w0 * a4[0].w;
    x.x = x.x * (1.f - w1 * e4[1].x) + w1 * a4[1].x;
    x.y = x.y * (1.f - w1 * e4[1].y) + w1 * a4[1].y;
    x.z = x.z * (1.f - w1 * e4[1].z) + w1 * a4[1].z;
    x.w = x.w * (1.f - w1 * e4[1].w) + w1 * a4[1].w;
    x.x = x.x * (1.f - w2 * e4[2].x) + w2 * a4[2].x;
    x.y = x.y * (1.f - w2 * e4[2].y) + w2 * a4[2].y;
    x.z = x.z * (1.f - w2 * e4[2].z) + w2 * a4[2].z;
    x.w = x.w * (1.f - w2 * e4[2].w) + w2 * a4[2].w;
    x.x = x.x * (1.f - w3 * e4[3].x) + w3 * a4[3].x;
    x.y = x.y * (1.f - w3 * e4[3].y) + w3 * a4[3].y;
    x.z = x.z * (1.f - w3 * e4[3].z) + w3 * a4[3].z;
    x.w = x.w * (1.f - w3 * e4[3].w) + w3 * a4[3].w;

    acc[0].x += w0 * x.x; acc[0].y += w0 * x.y; acc[0].z += w0 * x.z; acc[0].w += w0 * x.w;
    acc[1].x += w1 * x.x; acc[1].y += w1 * x.y; acc[1].z += w1 * x.z; acc[1].w += w1 * x.w;
    acc[2].x += w2 * x.x; acc[2].y += w2 * x.y; acc[2].z += w2 * x.z; acc[2].w += w2 * x.w;
    acc[3].x += w3 * x.x; acc[3].y += w3 * x.y; acc[3].z += w3 * x.z; acc[3].w += w3 * x.w;
  }

  // reduce rr pairs within each wave (lanes 0..31 keep the pair sum)
#pragma unroll
  for (int h = 0; h < H_; ++h) {
    acc[h].x += __shfl_xor(acc[h].x, 32, 64);
    acc[h].y += __shfl_xor(acc[h].y, 32, 64);
    acc[h].z += __shfl_xor(acc[h].z, 32, 64);
    acc[h].w += __shfl_xor(acc[h].w, 32, 64);
  }
  if (lane < 32) {
#pragma unroll
    for (int h = 0; h < H_; ++h) {
      red[wv * 512 + (h * 4 + 0) * 32 + lane] = acc[h].x;
      red[wv * 512 + (h * 4 + 1) * 32 + lane] = acc[h].y;
      red[wv * 512 + (h * 4 + 2) * 32 + lane] = acc[h].z;
      red[wv * 512 + (h * 4 + 3) * 32 + lane] = acc[h].w;
    }
  }
  __syncthreads();

  for (int j = tid; j < 512; j += 256) {
    const float val = red[j] + red[512 + j] + red[1024 + j] + red[1536 + j];
    const int h = j >> 7, comp = (j >> 5) & 3, cc = j & 31;
    atomicAdd(&out[b * H_ * M_ + h * M_ + cc * 4 + comp], val);
  }
}

extern "C" void kernel_launch(void* const* d_in, const int* in_sizes, int n_in,
                              void* d_out, int out_size, void* d_ws, size_t ws_size,
                              hipStream_t stream) {
  const float* mem  = (const float*)d_in[0];
  const float* kk   = (const float*)d_in[1];
  const float* beta = (const float*)d_in[2];
  const float* er   = (const float*)d_in[3];
  const float* ad   = (const float*)d_in[4];
  float* out = (float*)d_out;

  float* sc = (float*)d_ws;                                        // (B,H,S), 2 MiB
  float* Zp = (float*)((char*)d_ws + (size_t)B_ * H_ * S_ * 4);    // (B,H,NB1)

  dim3 g1(NB1, B_);         // 32 x 32 = 1024 blocks
  k_scores<<<g1, 256, 0, stream>>>(mem, kk, beta, sc, Zp, out);

  dim3 g3(S_ / ST3, B_);    // 32 x 32 = 1024 blocks, same shape as k1
  k_writeread<<<g3, 256, 0, stream>>>(mem, sc, Zp, er, ad, out);
}